// Round 7
// baseline (49809.067 us; speedup 1.0000x reference)
//
#include <hip/hip_runtime.h>
#include <cstdint>

#define NROWS 10000
#define DIM   784
#define CAND  150
#define MOUT  10
#define KMAX  64
#define TOT_W 117600   // DIM*CAND
#define TOT_B 150
#define BR 64          // rows per GEMM block
#define BC 160         // padded candidate cols
#define KT 16          // k tile
#define NBLK 157       // ceil(10000/64)
#define NTB 40         // t-blocks in qrall (256 rows each)
#define GENB 460       // gen blocks in qrall

// ---------------- Threefry-2x32 (exact JAX partitionable semantics) ----------------
#define RND_(r) { x0 += x1; x1 = (x1 << r) | (x1 >> (32 - r)); x1 ^= x0; }

__device__ __host__ inline void threefry2x32(uint32_t k0, uint32_t k1,
                                             uint32_t c0, uint32_t c1,
                                             uint32_t* o0, uint32_t* o1) {
  uint32_t ks2 = 0x1BD11BDAu ^ k0 ^ k1;
  uint32_t x0 = c0 + k0, x1 = c1 + k1;
  RND_(13) RND_(15) RND_(26) RND_(6)
  x0 += k1;  x1 += ks2 + 1u;
  RND_(17) RND_(29) RND_(16) RND_(24)
  x0 += ks2; x1 += k0 + 2u;
  RND_(13) RND_(15) RND_(26) RND_(6)
  x0 += k0;  x1 += k1 + 3u;
  RND_(17) RND_(29) RND_(16) RND_(24)
  x0 += k1;  x1 += ks2 + 4u;
  RND_(13) RND_(15) RND_(26) RND_(6)
  x0 += ks2; x1 += k0 + 5u;
  *o0 = x0; *o1 = x1;
}

__device__ inline float uni01(uint32_t bits) {
  uint32_t fb = (bits >> 9) | 0x3F800000u;
  return __uint_as_float(fb) - 1.0f;
}

__device__ inline float scale_of(int j) {
  return (j < 50) ? 0.5f : ((j < 100) ? 1.0f : 5.0f);
}

__device__ inline void gen_one(int f, uint32_t kw0, uint32_t kw1, uint32_t kb0, uint32_t kb1,
                               float* __restrict__ Wr, float* __restrict__ br) {
  if (f < TOT_W) {
    uint32_t o0, o1;
    threefry2x32(kw0, kw1, 0u, (uint32_t)f, &o0, &o1);
    float u = uni01(o0 ^ o1);
    int j = f % CAND;
    Wr[f] = scale_of(j) * (2.0f * u - 1.0f);
  } else if (f < TOT_W + TOT_B) {
    int g = f - TOT_W;
    uint32_t o0, o1;
    threefry2x32(kb0, kb1, 0u, (uint32_t)g, &o0, &o1);
    float u = uni01(o0 ^ o1);
    br[g] = scale_of(g) * (2.0f * u - 1.0f);
  }
}

// ---------------- init: zero counters ----------------
__global__ __launch_bounds__(64) void init_kern(unsigned* __restrict__ counters) {
  if (threadIdx.x < 2) counters[threadIdx.x] = 0u;
}

// ---------------- standalone W/b gen (step 0 only) ----------------
__global__ __launch_bounds__(256) void gen_rand_kern(float* __restrict__ Wr, float* __restrict__ br,
                                                     uint32_t kw0, uint32_t kw1,
                                                     uint32_t kb0, uint32_t kb1) {
  int f = blockIdx.x * 256 + threadIdx.x;
  gen_one(f, kw0, kw1, kb0, kb1, Wr, br);
}

// ---------------- kernel 1: e-compute + GEMM + partials + (last block) score/pick ----------------
__global__ __launch_bounds__(256) void gemm_score_kern(
    const float* __restrict__ X, const float* __restrict__ Y,
    const float* __restrict__ Hm, const float* __restrict__ beta,
    const float* __restrict__ Wr, const float* __restrict__ br_,
    float* __restrict__ h_col, float* __restrict__ part1t,
    float* __restrict__ outW, float* __restrict__ outb, int* __restrict__ ibest,
    unsigned* __restrict__ counter, int kprev, int k) {
  __shared__ __align__(16) float smem[7040];
  __shared__ float et[BR][MOUT];
  __shared__ int lastFlag;
  float* Xt = smem;            // [KT][BR]
  float* Wt = smem + 1024;     // [KT][BC]
  float* red = smem;           // [4][BC*11] aliased after compute

  int tid = threadIdx.x;
  int ty = tid >> 5, tx = tid & 31;
  int row0 = blockIdx.x * BR;
  int nr = NROWS - row0; if (nr > BR) nr = BR;
  bool full = (nr == BR);

  // ---- prologue: et = Y - H*beta (bitwise same chain as old upd_gen) ----
  if (tid < BR) {
    int row = row0 + tid;
    if (row < NROWS) {
      float s[10];
#pragma unroll
      for (int c = 0; c < 10; ++c) s[c] = 0.f;
      for (int j = 0; j <= kprev; ++j) {
        float hv = Hm[(size_t)j * NROWS + row];
#pragma unroll
        for (int c = 0; c < 10; ++c) s[c] = fmaf(hv, beta[j * 10 + c], s[c]);
      }
#pragma unroll
      for (int c = 0; c < 10; ++c) et[tid][c] = Y[(size_t)row * MOUT + c] - s[c];
    } else {
#pragma unroll
      for (int c = 0; c < 10; ++c) et[tid][c] = 0.f;
    }
  }

  float bbv[5];
#pragma unroll
  for (int cl = 0; cl < 5; ++cl) {
    int c = tx + 32 * cl;
    bbv[cl] = (c < CAND) ? br_[c] : 0.f;
  }

  float acc[8][5];
#pragma unroll
  for (int r = 0; r < 8; ++r)
#pragma unroll
    for (int cl = 0; cl < 5; ++cl) acc[r][cl] = 0.f;

  int rstage = tid >> 2;
  int qg = (tid & 3) * 4;
  int rclamp = rstage < nr ? rstage : nr - 1;
  const float* Xrow = X + (size_t)(row0 + rclamp) * DIM;

  for (int kk = 0; kk < DIM; kk += KT) {
    __syncthreads();
    float4 xv4 = *(const float4*)(Xrow + kk + qg);
    Xt[(qg + 0) * BR + rstage] = xv4.x;
    Xt[(qg + 1) * BR + rstage] = xv4.y;
    Xt[(qg + 2) * BR + rstage] = xv4.z;
    Xt[(qg + 3) * BR + rstage] = xv4.w;
    for (int idx = tid; idx < KT * BC; idx += 256) {
      int q = idx / BC, c = idx - q * BC;
      Wt[idx] = (c < CAND) ? Wr[(size_t)(kk + q) * CAND + c] : 0.f;
    }
    __syncthreads();
#pragma unroll
    for (int q = 0; q < KT; ++q) {
      float xv[8];
      *(float4*)&xv[0] = *(const float4*)&Xt[q * BR + ty * 8];
      *(float4*)&xv[4] = *(const float4*)&Xt[q * BR + ty * 8 + 4];
      float wv[5];
#pragma unroll
      for (int cl = 0; cl < 5; ++cl) wv[cl] = Wt[q * BC + tx + 32 * cl];
#pragma unroll
      for (int r = 0; r < 8; ++r)
#pragma unroll
        for (int cl = 0; cl < 5; ++cl)
          acc[r][cl] = fmaf(xv[r], wv[cl], acc[r][cl]);
    }
  }

  __syncthreads();   // Xt/Wt dead; red reusable; et ordered

#pragma unroll
  for (int cl = 0; cl < 5; ++cl) {
    int c = tx + 32 * cl;
    float hv[8];
#pragma unroll
    for (int r = 0; r < 8; ++r)
      hv[r] = 1.0f / (1.0f + expf(-(acc[r][cl] + bbv[cl])));
    if (c < CAND) {
      float* dst = h_col + (size_t)c * NROWS + row0 + ty * 8;
      if (full) {
        float4 a = {hv[0], hv[1], hv[2], hv[3]};
        float4 b4 = {hv[4], hv[5], hv[6], hv[7]};
        *(float4*)dst = a;
        *(float4*)(dst + 4) = b4;
      } else {
#pragma unroll
        for (int r = 0; r < 8; ++r)
          if (ty * 8 + r < nr) dst[r] = hv[r];
      }
    }
    float hh = 0.f, eth[10];
#pragma unroll
    for (int j = 0; j < 10; ++j) eth[j] = 0.f;
#pragma unroll
    for (int r = 0; r < 8; ++r) {
      if (full || ty * 8 + r < nr) {
        hh = fmaf(hv[r], hv[r], hh);
#pragma unroll
        for (int j = 0; j < 10; ++j) eth[j] = fmaf(et[ty * 8 + r][j], hv[r], eth[j]);
      }
    }
    hh += __shfl_xor(hh, 32);
#pragma unroll
    for (int j = 0; j < 10; ++j) eth[j] += __shfl_xor(eth[j], 32);
    if (!(ty & 1) && c < CAND) {
      float* dstr = red + (ty >> 1) * 1760 + c * 11;
      dstr[0] = hh;
#pragma unroll
      for (int j = 0; j < 10; ++j) dstr[1 + j] = eth[j];
    }
  }
  __syncthreads();
  for (int idx = tid; idx < CAND * 11; idx += 256) {
    float s = red[idx] + red[1760 + idx] + red[3520 + idx] + red[5280 + idx];
    part1t[(size_t)idx * NBLK + blockIdx.x] = s;
  }

  // ---- last-done block: reduce part1t, v, argmax, record ----
  __syncthreads();
  if (tid == 0) {
    __threadfence();
    unsigned d = __hip_atomic_fetch_add(counter, 1u, __ATOMIC_ACQ_REL, __HIP_MEMORY_SCOPE_AGENT);
    lastFlag = (d == NBLK - 1) ? 1 : 0;
  }
  __syncthreads();
  if (!lastFlag) return;
  if (tid == 0) { __threadfence(); *counter = 0u; }

  float* sums = smem;                 // [1650]
  float* vbuf = smem + 1664;          // [150]
  __shared__ int sbest;
  for (int idx = tid; idx < CAND * 11; idx += 256) {
    const float* p = part1t + (size_t)idx * NBLK;
    float s = 0.f;
    for (int b2 = 0; b2 < NBLK; ++b2) s += p[b2];
    sums[idx] = s;
  }
  __syncthreads();
  if (tid < CAND) {
    float hh = sums[tid * 11];
    float accv = 0.f;
#pragma unroll
    for (int c = 0; c < 10; ++c) { float d = sums[tid * 11 + 1 + c]; accv += (d * d) / hh; }
    vbuf[tid] = accv / 10.0f;
  }
  __syncthreads();
  if (tid == 0) {
    float bv = vbuf[0]; int bi = 0;
    for (int c = 1; c < CAND; ++c) {
      float v = vbuf[c];
      if (v > bv) { bv = v; bi = c; }
    }
    sbest = bi; *ibest = bi; outb[k] = br_[bi];
  }
  __syncthreads();
  int best = sbest;
  for (int i = tid; i < DIM; i += 256) outW[(size_t)i * KMAX + k] = Wr[(size_t)i * CAND + best];
}

// ---------------- kernel 2: full QR step (+ next-step W/b gen on extra blocks) ----------------
// Qm stores UNNORMALIZED t columns; r2g[j] = ||t_j||. Deferred normalization:
// r1[j] = (t_j . h)/r2g[j]; projection coef[j] = r1[j]/r2g[j].
__global__ __launch_bounds__(256) void qrall_kern(
    const float* __restrict__ h_col, const float* __restrict__ Y,
    float* __restrict__ Hm, float* __restrict__ Qm, float* __restrict__ r2g,
    float* __restrict__ Rm, float* __restrict__ QT, float* __restrict__ scal,
    float* __restrict__ outBeta, float* __restrict__ part2,
    const int* __restrict__ ibest, unsigned* __restrict__ counter,
    float* __restrict__ Wr, float* __restrict__ br,
    uint32_t kw0, uint32_t kw1, uint32_t kb0, uint32_t kb1, int k) {
  int b = blockIdx.x, tid = threadIdx.x;
  if (b >= NTB) {
    // ---- gen W/b for next step ----
    int f = (b - NTB) * 256 + tid;
    gen_one(f, kw0, kw1, kb0, kb1, Wr, br);
    return;
  }

  __shared__ float r1s[KMAX];
  __shared__ float coef[KMAX];
  __shared__ float wred[4][23];
  __shared__ int lastFlag;
  int best = *ibest;
  const float* hc_g = h_col + (size_t)best * NROWS;

  // copy H column slice
  int i = b * 256 + tid;
  if (i < NROWS) Hm[(size_t)k * NROWS + i] = hc_g[i];

  // r1 (redundant per block, deterministic identical): wave w handles j = w, w+4, ...
  int wid = tid >> 6, lane = tid & 63;
  for (int j = wid; j < k; j += 4) {
    const float* tj = Qm + (size_t)j * NROWS;
    float s = 0.f;
    for (int ii = lane; ii < NROWS; ii += 64)
      s = fmaf(tj[ii], hc_g[ii], s);
    s += __shfl_xor(s, 32); s += __shfl_xor(s, 16); s += __shfl_xor(s, 8);
    s += __shfl_xor(s, 4);  s += __shfl_xor(s, 2);  s += __shfl_xor(s, 1);
    if (lane == 0) {
      float r2j = r2g[j];
      float r1j = s / r2j;
      r1s[j] = r1j;
      coef[j] = r1j / r2j;
    }
  }
  __syncthreads();

  // t for my row; partials
  float tval = 0.f, hc = 0.f, h0 = 0.f;
  float yv[10];
#pragma unroll
  for (int c = 0; c < 10; ++c) yv[c] = 0.f;
  if (i < NROWS) {
    hc = hc_g[i];
    float s = 0.f;
    for (int jj = 0; jj < k; ++jj) s = fmaf(Qm[(size_t)jj * NROWS + i], coef[jj], s);
    tval = hc - s;
    Qm[(size_t)k * NROWS + i] = tval;
#pragma unroll
    for (int c = 0; c < 10; ++c) yv[c] = Y[(size_t)i * MOUT + c];
    if (k == 1) h0 = Hm[i];
  }

  int np = (k == 1) ? 23 : 11;
  float p[23];
  p[0] = tval * tval;
#pragma unroll
  for (int c = 0; c < 10; ++c) p[1 + c] = tval * yv[c];
  if (k == 1) {
    p[11] = hc * hc;
    p[12] = h0 * hc;
#pragma unroll
    for (int c = 0; c < 10; ++c) p[13 + c] = hc * yv[c];
  }
  for (int c = 0; c < np; ++c) {
    float v = p[c];
    v += __shfl_xor(v, 32); v += __shfl_xor(v, 16); v += __shfl_xor(v, 8);
    v += __shfl_xor(v, 4);  v += __shfl_xor(v, 2);  v += __shfl_xor(v, 1);
    if (lane == 0) wred[wid][c] = v;
  }
  __syncthreads();
  if (tid < np) part2[b * 23 + tid] = wred[0][tid] + wred[1][tid] + wred[2][tid] + wred[3][tid];

  // ---- last-done block: finalize ----
  __syncthreads();
  if (tid == 0) {
    __threadfence();
    unsigned d = __hip_atomic_fetch_add(counter, 1u, __ATOMIC_ACQ_REL, __HIP_MEMORY_SCOPE_AGENT);
    lastFlag = (d == NTB - 1) ? 1 : 0;
  }
  __syncthreads();
  if (!lastFlag) return;
  if (tid == 0) { __threadfence(); *counter = 0u; }

  __shared__ float vals[23];
  __shared__ float bsh[KMAX * 10];
  if (tid < np) {
    float s = 0.f;
    for (int b2 = 0; b2 < NTB; ++b2) s += part2[b2 * 23 + tid];
    vals[tid] = s;
  }
  __syncthreads();
  float r2 = sqrtf(vals[0]);
  if (tid < k) Rm[tid * KMAX + k] = r1s[tid];
  if (tid == 0) { Rm[k * KMAX + k] = r2; r2g[k] = r2; }
  if (tid < 10) QT[k * 10 + tid] = vals[1 + tid] / r2;
  if (k == 0 && tid < 11) scal[1 + tid] = vals[tid];
  __syncthreads();
  if (k == 0) {
    if (tid < 10) outBeta[tid] = (1.0f / vals[0]) * vals[1 + tid];
  } else if (k == 1) {
    if (tid < 10) {
      float g00 = scal[1], g0y = scal[2 + tid];
      float s11 = vals[11], s01 = vals[12], s1y = vals[13 + tid];
      float det = g00 * s11 - s01 * s01;
      float i00 = s11 / det, i01 = -s01 / det, i11 = g00 / det;
      outBeta[tid]      = i00 * g0y + i01 * s1y;
      outBeta[10 + tid] = i01 * g0y + i11 * s1y;
    }
  } else {
    if (tid < 10) {
      for (int row = k; row >= 0; --row) {
        float s = QT[row * 10 + tid];
        for (int jj = row + 1; jj <= k; ++jj) s = fmaf(-Rm[row * KMAX + jj], bsh[jj * 10 + tid], s);
        float bv = s / Rm[row * KMAX + row];
        bsh[row * 10 + tid] = bv;
        outBeta[row * 10 + tid] = bv;
      }
    }
  }
}

// ---------------- host ----------------
extern "C" void kernel_launch(void* const* d_in, const int* in_sizes, int n_in,
                              void* d_out, int out_size, void* d_ws, size_t ws_size,
                              hipStream_t stream) {
  const float* X = (const float*)d_in[0];
  const float* Y = (const float*)d_in[1];
  float* out = (float*)d_out;
  float* outW    = out;
  float* outb    = out + (size_t)DIM * KMAX;
  float* outBeta = outb + KMAX;

  float* ws = (float*)d_ws;
  size_t off = 0;
  float* h_col = ws + off; off += (size_t)NROWS * CAND;
  float* Wr    = ws + off; off += TOT_W;
  float* br    = ws + off; off += 256;
  float* Hm    = ws + off; off += (size_t)KMAX * NROWS;
  float* Qm    = ws + off; off += (size_t)KMAX * NROWS;
  float* Rm    = ws + off; off += (size_t)KMAX * KMAX;
  float* QT    = ws + off; off += (size_t)KMAX * MOUT;
  float* r2g   = ws + off; off += KMAX;
  float* part1t = ws + off; off += (size_t)CAND * 11 * NBLK;
  float* part2  = ws + off; off += (size_t)NTB * 23;
  float* scal   = ws + off; off += 16;
  int*   ibest  = (int*)(ws + off); off += 4;
  unsigned* counters = (unsigned*)(ws + off); off += 4;  // [0]=gemm, [1]=qrall

  // precompute key chain on host (bit-exact JAX split semantics)
  uint32_t kws0[KMAX], kws1[KMAX], kbs0[KMAX], kbs1[KMAX];
  uint32_t key0 = 0u, key1 = 42u;
  for (int k = 0; k < KMAX; ++k) {
    uint32_t o0[3], o1[3];
    for (int t = 0; t < 3; ++t)
      threefry2x32(key0, key1, 0u, (uint32_t)t, &o0[t], &o1[t]);
    kws0[k] = o0[1]; kws1[k] = o1[1]; kbs0[k] = o0[2]; kbs1[k] = o1[2];
    key0 = o0[0]; key1 = o1[0];
  }

  init_kern<<<1, 64, 0, stream>>>(counters);
  gen_rand_kern<<<(TOT_W + TOT_B + 255) / 256, 256, 0, stream>>>(Wr, br, kws0[0], kws1[0], kbs0[0], kbs1[0]);

  for (int k = 0; k < KMAX; ++k) {
    gemm_score_kern<<<NBLK, 256, 0, stream>>>(X, Y, Hm, outBeta, Wr, br,
                                              h_col, part1t, outW, outb, ibest,
                                              &counters[0], k - 1, k);
    bool genNext = (k + 1 < KMAX);
    int nb = genNext ? (NTB + GENB) : NTB;
    int kn = genNext ? (k + 1) : 0;
    qrall_kern<<<nb, 256, 0, stream>>>(h_col, Y, Hm, Qm, r2g, Rm, QT, scal,
                                       outBeta, part2, ibest, &counters[1],
                                       Wr, br, kws0[kn], kws1[kn], kbs0[kn], kbs1[kn], k);
  }
}

// Round 8
// 28630.716 us; speedup vs baseline: 1.7397x; 1.7397x over previous
//
#include <hip/hip_runtime.h>
#include <cstdint>

#define NROWS 10000
#define DIM   784
#define CAND  150
#define MOUT  10
#define KMAX  64
#define TOT_W 117600   // DIM*CAND
#define TOT_B 150
#define BR 64          // rows per GEMM block
#define BC 160         // padded candidate cols
#define KT 16          // k tile
#define NBLK 157       // ceil(10000/64)
#define NTB 40         // t-blocks (256 rows each)
#define GENB 460       // gen blocks riding in qr_tf
#define P1STRIDE 1664  // padded part1 row stride (floats)

// ---------------- Threefry-2x32 (exact JAX partitionable semantics) ----------------
#define RND_(r) { x0 += x1; x1 = (x1 << r) | (x1 >> (32 - r)); x1 ^= x0; }

__device__ __host__ inline void threefry2x32(uint32_t k0, uint32_t k1,
                                             uint32_t c0, uint32_t c1,
                                             uint32_t* o0, uint32_t* o1) {
  uint32_t ks2 = 0x1BD11BDAu ^ k0 ^ k1;
  uint32_t x0 = c0 + k0, x1 = c1 + k1;
  RND_(13) RND_(15) RND_(26) RND_(6)
  x0 += k1;  x1 += ks2 + 1u;
  RND_(17) RND_(29) RND_(16) RND_(24)
  x0 += ks2; x1 += k0 + 2u;
  RND_(13) RND_(15) RND_(26) RND_(6)
  x0 += k0;  x1 += k1 + 3u;
  RND_(17) RND_(29) RND_(16) RND_(24)
  x0 += k1;  x1 += ks2 + 4u;
  RND_(13) RND_(15) RND_(26) RND_(6)
  x0 += ks2; x1 += k0 + 5u;
  *o0 = x0; *o1 = x1;
}

__device__ inline float uni01(uint32_t bits) {
  uint32_t fb = (bits >> 9) | 0x3F800000u;
  return __uint_as_float(fb) - 1.0f;
}

__device__ inline float scale_of(int j) {
  return (j < 50) ? 0.5f : ((j < 100) ? 1.0f : 5.0f);
}

__device__ inline void gen_one(int f, uint32_t kw0, uint32_t kw1, uint32_t kb0, uint32_t kb1,
                               float* __restrict__ Wr, float* __restrict__ br) {
  if (f < TOT_W) {
    uint32_t o0, o1;
    threefry2x32(kw0, kw1, 0u, (uint32_t)f, &o0, &o1);
    float u = uni01(o0 ^ o1);
    int j = f % CAND;
    Wr[f] = scale_of(j) * (2.0f * u - 1.0f);
  } else if (f < TOT_W + TOT_B) {
    int g = f - TOT_W;
    uint32_t o0, o1;
    threefry2x32(kb0, kb1, 0u, (uint32_t)g, &o0, &o1);
    float u = uni01(o0 ^ o1);
    br[g] = scale_of(g) * (2.0f * u - 1.0f);
  }
}

__global__ __launch_bounds__(64) void init_kern(unsigned* __restrict__ counters) {
  if (threadIdx.x < 2) counters[threadIdx.x] = 0u;
}

__global__ __launch_bounds__(256) void gen_rand_kern(float* __restrict__ Wr, float* __restrict__ br,
                                                     uint32_t kw0, uint32_t kw1,
                                                     uint32_t kb0, uint32_t kb1) {
  int f = blockIdx.x * 256 + threadIdx.x;
  gen_one(f, kw0, kw1, kb0, kb1, Wr, br);
}

// ---------------- kernel A: e-compute + GEMM + partials + (last block) score/pick ----------------
// Thread-tile: 8 rows (ty*8..) x 5 cols {tx*4+0..3, 128+tx}. h per-element fmaf chain bitwise-stable.
__global__ __launch_bounds__(256) void gemm_score_kern(
    const float* __restrict__ X, const float* __restrict__ Y,
    const float* __restrict__ Hm, const float* __restrict__ beta,
    const float* __restrict__ Wr, const float* __restrict__ br_,
    float* __restrict__ h_col, float* __restrict__ part1,
    float* __restrict__ outW, float* __restrict__ outb, int* __restrict__ ibest,
    unsigned* __restrict__ counter, int kprev, int k) {
  __shared__ __align__(16) float smem[7040];
  __shared__ float et[BR][MOUT];
  __shared__ int lastFlag;
  float* Xt = smem;            // [KT][BR]
  float* Wt = smem + 1024;     // [KT][BC]
  float* red = smem;           // [4][1760] aliased after compute

  int tid = threadIdx.x;
  int ty = tid >> 5, tx = tid & 31;
  int row0 = blockIdx.x * BR;
  int nr = NROWS - row0; if (nr > BR) nr = BR;
  bool full = (nr == BR);

  // ---- prologue: et = Y - H*beta (serial-j chain, bitwise same as validated) ----
  if (tid < BR) {
    int row = row0 + tid;
    if (row < NROWS) {
      float s[10];
#pragma unroll
      for (int c = 0; c < 10; ++c) s[c] = 0.f;
#pragma unroll 4
      for (int j = 0; j <= kprev; ++j) {
        float hv = Hm[(size_t)j * NROWS + row];
#pragma unroll
        for (int c = 0; c < 10; ++c) s[c] = fmaf(hv, beta[j * 10 + c], s[c]);
      }
#pragma unroll
      for (int c = 0; c < 10; ++c) et[tid][c] = Y[(size_t)row * MOUT + c] - s[c];
    } else {
#pragma unroll
      for (int c = 0; c < 10; ++c) et[tid][c] = 0.f;
    }
  }

  // column mapping per thread
  int cmap[5];
#pragma unroll
  for (int cl = 0; cl < 4; ++cl) cmap[cl] = tx * 4 + cl;   // 0..127, always < CAND
  cmap[4] = 128 + tx;                                       // 128..159, masked

  float bbv[5];
#pragma unroll
  for (int cl = 0; cl < 5; ++cl)
    bbv[cl] = (cmap[cl] < CAND) ? br_[cmap[cl]] : 0.f;

  float acc[8][5];
#pragma unroll
  for (int r = 0; r < 8; ++r)
#pragma unroll
    for (int cl = 0; cl < 5; ++cl) acc[r][cl] = 0.f;

  int rstage = tid >> 2;
  int qg = (tid & 3) * 4;
  int rclamp = rstage < nr ? rstage : nr - 1;
  const float* Xrow = X + (size_t)(row0 + rclamp) * DIM;

  for (int kk = 0; kk < DIM; kk += KT) {
    __syncthreads();
    float4 xv4 = *(const float4*)(Xrow + kk + qg);
    Xt[(qg + 0) * BR + rstage] = xv4.x;
    Xt[(qg + 1) * BR + rstage] = xv4.y;
    Xt[(qg + 2) * BR + rstage] = xv4.z;
    Xt[(qg + 3) * BR + rstage] = xv4.w;
    // stage W via float2 (global rows 8B-aligned for even c)
    for (int idx2 = tid; idx2 < KT * BC / 2; idx2 += 256) {
      int q = idx2 / (BC / 2), c2 = (idx2 - q * (BC / 2)) * 2;
      float2 wv2;
      if (c2 + 1 < CAND) wv2 = *(const float2*)&Wr[(size_t)(kk + q) * CAND + c2];
      else { wv2.x = (c2 < CAND) ? Wr[(size_t)(kk + q) * CAND + c2] : 0.f; wv2.y = 0.f; }
      *(float2*)&Wt[q * BC + c2] = wv2;
    }
    __syncthreads();
#pragma unroll
    for (int q = 0; q < KT; ++q) {
      float xv[8];
      *(float4*)&xv[0] = *(const float4*)&Xt[q * BR + ty * 8];
      *(float4*)&xv[4] = *(const float4*)&Xt[q * BR + ty * 8 + 4];
      float wv[5];
      *(float4*)&wv[0] = *(const float4*)&Wt[q * BC + tx * 4];  // 16B aligned
      wv[4] = Wt[q * BC + 128 + tx];
#pragma unroll
      for (int r = 0; r < 8; ++r)
#pragma unroll
        for (int cl = 0; cl < 5; ++cl)
          acc[r][cl] = fmaf(xv[r], wv[cl], acc[r][cl]);
    }
  }

  __syncthreads();   // Xt/Wt dead; red reusable; et ready

#pragma unroll
  for (int cl = 0; cl < 5; ++cl) {
    int c = cmap[cl];
    float hv[8];
#pragma unroll
    for (int r = 0; r < 8; ++r)
      hv[r] = 1.0f / (1.0f + expf(-(acc[r][cl] + bbv[cl])));
    if (c < CAND) {
      float* dst = h_col + (size_t)c * NROWS + row0 + ty * 8;
      if (full) {
        float4 a = {hv[0], hv[1], hv[2], hv[3]};
        float4 b4 = {hv[4], hv[5], hv[6], hv[7]};
        *(float4*)dst = a;
        *(float4*)(dst + 4) = b4;
      } else {
#pragma unroll
        for (int r = 0; r < 8; ++r)
          if (ty * 8 + r < nr) dst[r] = hv[r];
      }
    }
    float hh = 0.f, eth[10];
#pragma unroll
    for (int j = 0; j < 10; ++j) eth[j] = 0.f;
#pragma unroll
    for (int r = 0; r < 8; ++r) {
      if (full || ty * 8 + r < nr) {
        hh = fmaf(hv[r], hv[r], hh);
#pragma unroll
        for (int j = 0; j < 10; ++j) eth[j] = fmaf(et[ty * 8 + r][j], hv[r], eth[j]);
      }
    }
    hh += __shfl_xor(hh, 32);
#pragma unroll
    for (int j = 0; j < 10; ++j) eth[j] += __shfl_xor(eth[j], 32);
    if (!(ty & 1) && c < CAND) {
      float* dstr = red + (ty >> 1) * 1760 + c * 11;
      dstr[0] = hh;
#pragma unroll
      for (int j = 0; j < 10; ++j) dstr[1 + j] = eth[j];
    }
  }
  __syncthreads();
  for (int idx = tid; idx < CAND * 11; idx += 256) {
    float s = red[idx] + red[1760 + idx] + red[3520 + idx] + red[5280 + idx];
    part1[(size_t)blockIdx.x * P1STRIDE + idx] = s;
  }

  // ---- last-done block: coalesced reduce, v, argmax, record ----
  __syncthreads();
  if (tid == 0) {
    __threadfence();
    unsigned d = __hip_atomic_fetch_add(counter, 1u, __ATOMIC_ACQ_REL, __HIP_MEMORY_SCOPE_AGENT);
    lastFlag = (d == NBLK - 1) ? 1 : 0;
  }
  __syncthreads();
  if (!lastFlag) return;
  if (tid == 0) { __threadfence(); *counter = 0u; }

  float acc7[7];
#pragma unroll
  for (int ii = 0; ii < 7; ++ii) acc7[ii] = 0.f;
  for (int b2 = 0; b2 < NBLK; ++b2) {
    const float* p = part1 + (size_t)b2 * P1STRIDE;
#pragma unroll
    for (int ii = 0; ii < 7; ++ii) {
      int idx = tid + ii * 256;
      if (idx < CAND * 11) acc7[ii] += p[idx];
    }
  }
  float* sums = smem;                 // [1650]
  float* vbuf = smem + 1664;          // [150]
  __shared__ int sbest;
#pragma unroll
  for (int ii = 0; ii < 7; ++ii) {
    int idx = tid + ii * 256;
    if (idx < CAND * 11) sums[idx] = acc7[ii];
  }
  __syncthreads();
  if (tid < CAND) {
    float hh = sums[tid * 11];
    float accv = 0.f;
#pragma unroll
    for (int c = 0; c < 10; ++c) { float d = sums[tid * 11 + 1 + c]; accv += (d * d) / hh; }
    vbuf[tid] = accv / 10.0f;
  }
  __syncthreads();
  if (tid == 0) {
    float bv = vbuf[0]; int bi = 0;
    for (int c = 1; c < CAND; ++c) {
      float v = vbuf[c];
      if (v > bv) { bv = v; bi = c; }
    }
    sbest = bi; *ibest = bi; outb[k] = br_[bi];
  }
  __syncthreads();
  int best = sbest;
  for (int i = tid; i < DIM; i += 256) outW[(size_t)i * KMAX + k] = Wr[(size_t)i * CAND + best];
}

// ---------------- kernel B: r1[j] = (t_j . h_c)/r2[j], one j per block; block k copies H col ----
__global__ __launch_bounds__(256) void qr_r1_kern(const float* __restrict__ h_col, float* __restrict__ Hm,
                                                  const float* __restrict__ Qm, const float* __restrict__ r2g,
                                                  float* __restrict__ r1g, const int* __restrict__ ibest, int k) {
  int j = blockIdx.x, tid = threadIdx.x;
  int best = *ibest;
  const float* hc = h_col + (size_t)best * NROWS;
  if (j == k) {
    for (int i = tid; i < NROWS; i += 256)
      Hm[(size_t)k * NROWS + i] = hc[i];
    return;
  }
  const float* tj = Qm + (size_t)j * NROWS;
  float local = 0.f;
#pragma unroll 4
  for (int i = tid; i < NROWS; i += 256)
    local = fmaf(tj[i], hc[i], local);
  local += __shfl_xor(local, 32); local += __shfl_xor(local, 16);
  local += __shfl_xor(local, 8);  local += __shfl_xor(local, 4);
  local += __shfl_xor(local, 2);  local += __shfl_xor(local, 1);
  __shared__ float wred[4];
  int wid = tid >> 6, lane = tid & 63;
  if (lane == 0) wred[wid] = local;
  __syncthreads();
  if (tid == 0) {
    float s = wred[0] + wred[1] + wred[2] + wred[3];
    r1g[j] = s / r2g[j];
  }
}

// ---------------- kernel C: t + partials + last-block finalize; gen blocks ride along ----------------
// Qm stores UNNORMALIZED t columns; coef[j] = r1[j]/r2[j].
__global__ __launch_bounds__(256) void qr_tf_kern(
    const float* __restrict__ h_col, const float* __restrict__ Y,
    const float* __restrict__ Hm, float* __restrict__ Qm,
    float* __restrict__ r2g, const float* __restrict__ r1g,
    float* __restrict__ Rm, float* __restrict__ QT, float* __restrict__ scal,
    float* __restrict__ outBeta, float* __restrict__ part2,
    const int* __restrict__ ibest, unsigned* __restrict__ counter,
    float* __restrict__ Wr, float* __restrict__ br,
    uint32_t kw0, uint32_t kw1, uint32_t kb0, uint32_t kb1, int k) {
  int b = blockIdx.x, tid = threadIdx.x;
  if (b >= NTB) {
    int f = (b - NTB) * 256 + tid;
    gen_one(f, kw0, kw1, kb0, kb1, Wr, br);
    return;
  }

  __shared__ float r1s[KMAX];
  __shared__ float coef[KMAX];
  __shared__ float wred[4][23];
  __shared__ int lastFlag;
  if (tid < k) {
    float r1v = r1g[tid];
    r1s[tid] = r1v;
    coef[tid] = r1v / r2g[tid];
  }
  __syncthreads();

  int best = *ibest;
  const float* hc_g = h_col + (size_t)best * NROWS;
  int i = b * 256 + tid;
  float tval = 0.f, hc = 0.f, h0 = 0.f;
  float yv[10];
#pragma unroll
  for (int c = 0; c < 10; ++c) yv[c] = 0.f;
  if (i < NROWS) {
    hc = hc_g[i];
    float s0 = 0.f, s1 = 0.f, s2 = 0.f, s3 = 0.f;
    int jj = 0;
    for (; jj + 3 < k; jj += 4) {
      s0 = fmaf(Qm[(size_t)jj * NROWS + i],       coef[jj],     s0);
      s1 = fmaf(Qm[(size_t)(jj + 1) * NROWS + i], coef[jj + 1], s1);
      s2 = fmaf(Qm[(size_t)(jj + 2) * NROWS + i], coef[jj + 2], s2);
      s3 = fmaf(Qm[(size_t)(jj + 3) * NROWS + i], coef[jj + 3], s3);
    }
    for (; jj < k; ++jj) s0 = fmaf(Qm[(size_t)jj * NROWS + i], coef[jj], s0);
    float s = (s0 + s1) + (s2 + s3);
    tval = hc - s;
    Qm[(size_t)k * NROWS + i] = tval;
#pragma unroll
    for (int c = 0; c < 10; ++c) yv[c] = Y[(size_t)i * MOUT + c];
    if (k == 1) h0 = Hm[i];
  }

  int np = (k == 1) ? 23 : 11;
  float p[23];
  p[0] = tval * tval;
#pragma unroll
  for (int c = 0; c < 10; ++c) p[1 + c] = tval * yv[c];
  if (k == 1) {
    p[11] = hc * hc;
    p[12] = h0 * hc;
#pragma unroll
    for (int c = 0; c < 10; ++c) p[13 + c] = hc * yv[c];
  }
  int wid = tid >> 6, lane = tid & 63;
  for (int c = 0; c < np; ++c) {
    float v = p[c];
    v += __shfl_xor(v, 32); v += __shfl_xor(v, 16); v += __shfl_xor(v, 8);
    v += __shfl_xor(v, 4);  v += __shfl_xor(v, 2);  v += __shfl_xor(v, 1);
    if (lane == 0) wred[wid][c] = v;
  }
  __syncthreads();
  if (tid < np) part2[b * 23 + tid] = wred[0][tid] + wred[1][tid] + wred[2][tid] + wred[3][tid];

  // ---- last-done block: finalize ----
  __syncthreads();
  if (tid == 0) {
    __threadfence();
    unsigned d = __hip_atomic_fetch_add(counter, 1u, __ATOMIC_ACQ_REL, __HIP_MEMORY_SCOPE_AGENT);
    lastFlag = (d == NTB - 1) ? 1 : 0;
  }
  __syncthreads();
  if (!lastFlag) return;
  if (tid == 0) { __threadfence(); *counter = 0u; }

  __shared__ float vals[23];
  __shared__ float bsh[KMAX * 10];
  if (tid < np) {
    float s = 0.f;
    for (int b2 = 0; b2 < NTB; ++b2) s += part2[b2 * 23 + tid];
    vals[tid] = s;
  }
  __syncthreads();
  float r2 = sqrtf(vals[0]);
  if (tid < k) Rm[tid * KMAX + k] = r1s[tid];
  if (tid == 0) { Rm[k * KMAX + k] = r2; r2g[k] = r2; }
  if (tid < 10) QT[k * 10 + tid] = vals[1 + tid] / r2;
  if (k == 0 && tid < 11) scal[1 + tid] = vals[tid];
  __syncthreads();
  if (k == 0) {
    if (tid < 10) outBeta[tid] = (1.0f / vals[0]) * vals[1 + tid];
  } else if (k == 1) {
    if (tid < 10) {
      float g00 = scal[1], g0y = scal[2 + tid];
      float s11 = vals[11], s01 = vals[12], s1y = vals[13 + tid];
      float det = g00 * s11 - s01 * s01;
      float i00 = s11 / det, i01 = -s01 / det, i11 = g00 / det;
      outBeta[tid]      = i00 * g0y + i01 * s1y;
      outBeta[10 + tid] = i01 * g0y + i11 * s1y;
    }
  } else {
    if (tid < 10) {
      for (int row = k; row >= 0; --row) {
        float s = QT[row * 10 + tid];
        for (int jj = row + 1; jj <= k; ++jj) s = fmaf(-Rm[row * KMAX + jj], bsh[jj * 10 + tid], s);
        float bv = s / Rm[row * KMAX + row];
        bsh[row * 10 + tid] = bv;
        outBeta[row * 10 + tid] = bv;
      }
    }
  }
}

// ---------------- host ----------------
extern "C" void kernel_launch(void* const* d_in, const int* in_sizes, int n_in,
                              void* d_out, int out_size, void* d_ws, size_t ws_size,
                              hipStream_t stream) {
  const float* X = (const float*)d_in[0];
  const float* Y = (const float*)d_in[1];
  float* out = (float*)d_out;
  float* outW    = out;
  float* outb    = out + (size_t)DIM * KMAX;
  float* outBeta = outb + KMAX;

  float* ws = (float*)d_ws;
  size_t off = 0;
  float* h_col = ws + off; off += (size_t)NROWS * CAND;
  float* Wr    = ws + off; off += TOT_W;
  float* br    = ws + off; off += 256;
  float* Hm    = ws + off; off += (size_t)KMAX * NROWS;
  float* Qm    = ws + off; off += (size_t)KMAX * NROWS;
  float* Rm    = ws + off; off += (size_t)KMAX * KMAX;
  float* QT    = ws + off; off += (size_t)KMAX * MOUT;
  float* r2g   = ws + off; off += KMAX;
  float* r1g   = ws + off; off += KMAX;
  float* part1 = ws + off; off += (size_t)NBLK * P1STRIDE;
  float* part2 = ws + off; off += (size_t)NTB * 23;
  float* scal  = ws + off; off += 16;
  int*   ibest = (int*)(ws + off); off += 4;
  unsigned* counters = (unsigned*)(ws + off); off += 4;  // [0]=gemm, [1]=qr_tf

  // precompute key chain on host (bit-exact JAX split semantics)
  uint32_t kws0[KMAX], kws1[KMAX], kbs0[KMAX], kbs1[KMAX];
  uint32_t key0 = 0u, key1 = 42u;
  for (int k = 0; k < KMAX; ++k) {
    uint32_t o0[3], o1[3];
    for (int t = 0; t < 3; ++t)
      threefry2x32(key0, key1, 0u, (uint32_t)t, &o0[t], &o1[t]);
    kws0[k] = o0[1]; kws1[k] = o1[1]; kbs0[k] = o0[2]; kbs1[k] = o1[2];
    key0 = o0[0]; key1 = o1[0];
  }

  init_kern<<<1, 64, 0, stream>>>(counters);
  gen_rand_kern<<<(TOT_W + TOT_B + 255) / 256, 256, 0, stream>>>(Wr, br, kws0[0], kws1[0], kbs0[0], kbs1[0]);

  for (int k = 0; k < KMAX; ++k) {
    gemm_score_kern<<<NBLK, 256, 0, stream>>>(X, Y, Hm, outBeta, Wr, br,
                                              h_col, part1, outW, outb, ibest,
                                              &counters[0], k - 1, k);
    qr_r1_kern<<<k + 1, 256, 0, stream>>>(h_col, Hm, Qm, r2g, r1g, ibest, k);
    bool genNext = (k + 1 < KMAX);
    int nb = genNext ? (NTB + GENB) : NTB;
    int kn = genNext ? (k + 1) : 0;
    qr_tf_kern<<<nb, 256, 0, stream>>>(h_col, Y, Hm, Qm, r2g, r1g, Rm, QT, scal,
                                       outBeta, part2, ibest, &counters[1],
                                       Wr, br, kws0[kn], kws1[kn], kbs0[kn], kbs1[kn], k);
  }
}

// Round 9
// 20120.926 us; speedup vs baseline: 2.4755x; 1.4229x over previous
//
#include <hip/hip_runtime.h>
#include <cstdint>

#define NROWS 10000
#define DIM   784
#define CAND  150
#define MOUT  10
#define KMAX  64
#define TOT_W 117600   // DIM*CAND
#define TOT_B 150
#define BR 64          // rows per GEMM block
#define BC 160         // padded candidate cols
#define KT 16          // k tile
#define NBLK 157       // ceil(10000/64)
#define NTB 40         // t-blocks (256 rows each)
#define GENB 460       // gen blocks riding in qr_tf
#define P1STRIDE 1664  // padded part1 row stride (floats)

// ---------------- Threefry-2x32 (exact JAX partitionable semantics) ----------------
#define RND_(r) { x0 += x1; x1 = (x1 << r) | (x1 >> (32 - r)); x1 ^= x0; }

__device__ __host__ inline void threefry2x32(uint32_t k0, uint32_t k1,
                                             uint32_t c0, uint32_t c1,
                                             uint32_t* o0, uint32_t* o1) {
  uint32_t ks2 = 0x1BD11BDAu ^ k0 ^ k1;
  uint32_t x0 = c0 + k0, x1 = c1 + k1;
  RND_(13) RND_(15) RND_(26) RND_(6)
  x0 += k1;  x1 += ks2 + 1u;
  RND_(17) RND_(29) RND_(16) RND_(24)
  x0 += ks2; x1 += k0 + 2u;
  RND_(13) RND_(15) RND_(26) RND_(6)
  x0 += k0;  x1 += k1 + 3u;
  RND_(17) RND_(29) RND_(16) RND_(24)
  x0 += k1;  x1 += ks2 + 4u;
  RND_(13) RND_(15) RND_(26) RND_(6)
  x0 += ks2; x1 += k0 + 5u;
  *o0 = x0; *o1 = x1;
}

__device__ inline float uni01(uint32_t bits) {
  uint32_t fb = (bits >> 9) | 0x3F800000u;
  return __uint_as_float(fb) - 1.0f;
}

__device__ inline float scale_of(int j) {
  return (j < 50) ? 0.5f : ((j < 100) ? 1.0f : 5.0f);
}

__device__ inline void gen_one(int f, uint32_t kw0, uint32_t kw1, uint32_t kb0, uint32_t kb1,
                               float* __restrict__ Wr, float* __restrict__ br) {
  if (f < TOT_W) {
    uint32_t o0, o1;
    threefry2x32(kw0, kw1, 0u, (uint32_t)f, &o0, &o1);
    float u = uni01(o0 ^ o1);
    int j = f % CAND;
    Wr[f] = scale_of(j) * (2.0f * u - 1.0f);
  } else if (f < TOT_W + TOT_B) {
    int g = f - TOT_W;
    uint32_t o0, o1;
    threefry2x32(kb0, kb1, 0u, (uint32_t)g, &o0, &o1);
    float u = uni01(o0 ^ o1);
    br[g] = scale_of(g) * (2.0f * u - 1.0f);
  }
}

__global__ __launch_bounds__(64) void init_kern(unsigned* __restrict__ counters) {
  if (threadIdx.x < 2) counters[threadIdx.x] = 0u;
}

__global__ __launch_bounds__(256) void gen_rand_kern(float* __restrict__ Wr, float* __restrict__ br,
                                                     uint32_t kw0, uint32_t kw1,
                                                     uint32_t kb0, uint32_t kb1) {
  int f = blockIdx.x * 256 + threadIdx.x;
  gen_one(f, kw0, kw1, kb0, kb1, Wr, br);
}

// ---------------- kernel A: e-compute + GEMM + partials + (last block) score/pick ----------------
// 512 threads = 8 waves (2/SIMD). Thread-tile: 4 rows (ty*4..) x 5 cols {tx*4+0..3, 128+tx}.
// Per-(row,col) fmaf chain strictly k-sequential -> h bitwise stable vs validated kernel.
__global__ __launch_bounds__(512, 2) void gemm_score_kern(
    const float* __restrict__ X, const float* __restrict__ Y,
    const float* __restrict__ Hm, const float* __restrict__ beta,
    const float* __restrict__ Wr, const float* __restrict__ br_,
    float* __restrict__ h_col, float* __restrict__ part1,
    float* __restrict__ outW, float* __restrict__ outb, int* __restrict__ ibest,
    unsigned* __restrict__ counter, int kprev, int k) {
  __shared__ __align__(16) float smem[14080];  // max(1024+2560, 8*1760)
  __shared__ float et[BR][MOUT];
  __shared__ int lastFlag;
  float* Xt = smem;            // [KT][BR]
  float* Wt = smem + 1024;     // [KT][BC]
  float* red = smem;           // [8][1760] aliased after compute

  int tid = threadIdx.x;
  int ty = tid >> 5, tx = tid & 31;     // ty 0..15
  int row0 = blockIdx.x * BR;
  int nr = NROWS - row0; if (nr > BR) nr = BR;
  bool full = (nr == BR);

  // ---- prologue: et = Y - H*beta (wave 0; serial-j chain, bitwise same as validated) ----
  if (tid < BR) {
    int row = row0 + tid;
    if (row < NROWS) {
      float s[10];
#pragma unroll
      for (int c = 0; c < 10; ++c) s[c] = 0.f;
#pragma unroll 4
      for (int j = 0; j <= kprev; ++j) {
        float hv = Hm[(size_t)j * NROWS + row];
#pragma unroll
        for (int c = 0; c < 10; ++c) s[c] = fmaf(hv, beta[j * 10 + c], s[c]);
      }
#pragma unroll
      for (int c = 0; c < 10; ++c) et[tid][c] = Y[(size_t)row * MOUT + c] - s[c];
    } else {
#pragma unroll
      for (int c = 0; c < 10; ++c) et[tid][c] = 0.f;
    }
  }

  int cmap[5];
#pragma unroll
  for (int cl = 0; cl < 4; ++cl) cmap[cl] = tx * 4 + cl;
  cmap[4] = 128 + tx;

  float bbv[5];
#pragma unroll
  for (int cl = 0; cl < 5; ++cl)
    bbv[cl] = (cmap[cl] < CAND) ? br_[cmap[cl]] : 0.f;

  float acc[4][5];
#pragma unroll
  for (int r = 0; r < 4; ++r)
#pragma unroll
    for (int cl = 0; cl < 5; ++cl) acc[r][cl] = 0.f;

  int rstage = tid >> 3;                 // 0..63
  int qg = (tid & 7) * 2;                // 0,2,..,14
  int rclamp = rstage < nr ? rstage : nr - 1;
  const float* Xrow = X + (size_t)(row0 + rclamp) * DIM;

  for (int kk = 0; kk < DIM; kk += KT) {
    __syncthreads();
    float2 xv2 = *(const float2*)(Xrow + kk + qg);
    Xt[(qg + 0) * BR + rstage] = xv2.x;
    Xt[(qg + 1) * BR + rstage] = xv2.y;
    for (int idx2 = tid; idx2 < KT * BC / 2; idx2 += 512) {
      int q = idx2 / (BC / 2), c2 = (idx2 - q * (BC / 2)) * 2;
      float2 wv2;
      if (c2 + 1 < CAND) wv2 = *(const float2*)&Wr[(size_t)(kk + q) * CAND + c2];
      else { wv2.x = (c2 < CAND) ? Wr[(size_t)(kk + q) * CAND + c2] : 0.f; wv2.y = 0.f; }
      *(float2*)&Wt[q * BC + c2] = wv2;
    }
    __syncthreads();
#pragma unroll
    for (int q = 0; q < KT; ++q) {
      float xv[4];
      *(float4*)&xv[0] = *(const float4*)&Xt[q * BR + ty * 4];
      float wv[5];
      *(float4*)&wv[0] = *(const float4*)&Wt[q * BC + tx * 4];
      wv[4] = Wt[q * BC + 128 + tx];
#pragma unroll
      for (int r = 0; r < 4; ++r)
#pragma unroll
        for (int cl = 0; cl < 5; ++cl)
          acc[r][cl] = fmaf(xv[r], wv[cl], acc[r][cl]);
    }
  }

  __syncthreads();   // Xt/Wt dead; red reusable; et ready

#pragma unroll
  for (int cl = 0; cl < 5; ++cl) {
    int c = cmap[cl];
    float hv[4];
#pragma unroll
    for (int r = 0; r < 4; ++r)
      hv[r] = 1.0f / (1.0f + expf(-(acc[r][cl] + bbv[cl])));
    if (c < CAND) {
      float* dst = h_col + (size_t)c * NROWS + row0 + ty * 4;
      if (full) {
        float4 a = {hv[0], hv[1], hv[2], hv[3]};
        *(float4*)dst = a;
      } else {
#pragma unroll
        for (int r = 0; r < 4; ++r)
          if (ty * 4 + r < nr) dst[r] = hv[r];
      }
    }
    float hh = 0.f, eth[10];
#pragma unroll
    for (int j = 0; j < 10; ++j) eth[j] = 0.f;
#pragma unroll
    for (int r = 0; r < 4; ++r) {
      if (full || ty * 4 + r < nr) {
        hh = fmaf(hv[r], hv[r], hh);
#pragma unroll
        for (int j = 0; j < 10; ++j) eth[j] = fmaf(et[ty * 4 + r][j], hv[r], eth[j]);
      }
    }
    hh += __shfl_xor(hh, 32);
#pragma unroll
    for (int j = 0; j < 10; ++j) eth[j] += __shfl_xor(eth[j], 32);
    if (!(ty & 1) && c < CAND) {
      float* dstr = red + (ty >> 1) * 1760 + c * 11;
      dstr[0] = hh;
#pragma unroll
      for (int j = 0; j < 10; ++j) dstr[1 + j] = eth[j];
    }
  }
  __syncthreads();
  for (int idx = tid; idx < CAND * 11; idx += 512) {
    float s = ((red[idx] + red[1760 + idx]) + (red[3520 + idx] + red[5280 + idx])) +
              ((red[7040 + idx] + red[8800 + idx]) + (red[10560 + idx] + red[12320 + idx]));
    part1[(size_t)blockIdx.x * P1STRIDE + idx] = s;
  }

  // ---- last-done block: coalesced reduce, v, argmax, record ----
  __syncthreads();
  if (tid == 0) {
    __threadfence();
    unsigned d = __hip_atomic_fetch_add(counter, 1u, __ATOMIC_ACQ_REL, __HIP_MEMORY_SCOPE_AGENT);
    lastFlag = (d == NBLK - 1) ? 1 : 0;
  }
  __syncthreads();
  if (!lastFlag) return;
  if (tid == 0) { __threadfence(); *counter = 0u; }

  float acc4[4];
#pragma unroll
  for (int ii = 0; ii < 4; ++ii) acc4[ii] = 0.f;
  for (int b2 = 0; b2 < NBLK; ++b2) {
    const float* p = part1 + (size_t)b2 * P1STRIDE;
#pragma unroll
    for (int ii = 0; ii < 4; ++ii) {
      int idx = tid + ii * 512;
      if (idx < CAND * 11) acc4[ii] += p[idx];
    }
  }
  float* sums = smem;                 // [1650]
  float* vbuf = smem + 1664;          // [150]
  __shared__ int sbest;
#pragma unroll
  for (int ii = 0; ii < 4; ++ii) {
    int idx = tid + ii * 512;
    if (idx < CAND * 11) sums[idx] = acc4[ii];
  }
  __syncthreads();
  if (tid < CAND) {
    float hh = sums[tid * 11];
    float accv = 0.f;
#pragma unroll
    for (int c = 0; c < 10; ++c) { float d = sums[tid * 11 + 1 + c]; accv += (d * d) / hh; }
    vbuf[tid] = accv / 10.0f;
  }
  __syncthreads();
  if (tid == 0) {
    float bv = vbuf[0]; int bi = 0;
    for (int c = 1; c < CAND; ++c) {
      float v = vbuf[c];
      if (v > bv) { bv = v; bi = c; }
    }
    sbest = bi; *ibest = bi; outb[k] = br_[bi];
  }
  __syncthreads();
  int best = sbest;
  for (int i = tid; i < DIM; i += 512) outW[(size_t)i * KMAX + k] = Wr[(size_t)i * CAND + best];
}

// ---------------- kernel B: r1[j] = (t_j . h_c)/r2[j], one j per block; block k copies H col ----
__global__ __launch_bounds__(256) void qr_r1_kern(const float* __restrict__ h_col, float* __restrict__ Hm,
                                                  const float* __restrict__ Qm, const float* __restrict__ r2g,
                                                  float* __restrict__ r1g, const int* __restrict__ ibest, int k) {
  int j = blockIdx.x, tid = threadIdx.x;
  int best = *ibest;
  const float* hc = h_col + (size_t)best * NROWS;
  if (j == k) {
    for (int i = tid; i < NROWS; i += 256)
      Hm[(size_t)k * NROWS + i] = hc[i];
    return;
  }
  const float* tj = Qm + (size_t)j * NROWS;
  float local = 0.f;
#pragma unroll 4
  for (int i = tid; i < NROWS; i += 256)
    local = fmaf(tj[i], hc[i], local);
  local += __shfl_xor(local, 32); local += __shfl_xor(local, 16);
  local += __shfl_xor(local, 8);  local += __shfl_xor(local, 4);
  local += __shfl_xor(local, 2);  local += __shfl_xor(local, 1);
  __shared__ float wred[4];
  int wid = tid >> 6, lane = tid & 63;
  if (lane == 0) wred[wid] = local;
  __syncthreads();
  if (tid == 0) {
    float s = wred[0] + wred[1] + wred[2] + wred[3];
    r1g[j] = s / r2g[j];
  }
}

// ---------------- kernel C: t + partials + last-block finalize; gen blocks ride along ----------------
__global__ __launch_bounds__(256) void qr_tf_kern(
    const float* __restrict__ h_col, const float* __restrict__ Y,
    const float* __restrict__ Hm, float* __restrict__ Qm,
    float* __restrict__ r2g, const float* __restrict__ r1g,
    float* __restrict__ Rm, float* __restrict__ QT, float* __restrict__ scal,
    float* __restrict__ outBeta, float* __restrict__ part2,
    const int* __restrict__ ibest, unsigned* __restrict__ counter,
    float* __restrict__ Wr, float* __restrict__ br,
    uint32_t kw0, uint32_t kw1, uint32_t kb0, uint32_t kb1, int k) {
  int b = blockIdx.x, tid = threadIdx.x;
  if (b >= NTB) {
    int f = (b - NTB) * 256 + tid;
    gen_one(f, kw0, kw1, kb0, kb1, Wr, br);
    return;
  }

  __shared__ float r1s[KMAX];
  __shared__ float coef[KMAX];
  __shared__ float wred[4][23];
  __shared__ int lastFlag;
  if (tid < k) {
    float r1v = r1g[tid];
    r1s[tid] = r1v;
    coef[tid] = r1v / r2g[tid];
  }
  __syncthreads();

  int best = *ibest;
  const float* hc_g = h_col + (size_t)best * NROWS;
  int i = b * 256 + tid;
  float tval = 0.f, hc = 0.f, h0 = 0.f;
  float yv[10];
#pragma unroll
  for (int c = 0; c < 10; ++c) yv[c] = 0.f;
  if (i < NROWS) {
    hc = hc_g[i];
    float s0 = 0.f, s1 = 0.f, s2 = 0.f, s3 = 0.f;
    int jj = 0;
    for (; jj + 3 < k; jj += 4) {
      s0 = fmaf(Qm[(size_t)jj * NROWS + i],       coef[jj],     s0);
      s1 = fmaf(Qm[(size_t)(jj + 1) * NROWS + i], coef[jj + 1], s1);
      s2 = fmaf(Qm[(size_t)(jj + 2) * NROWS + i], coef[jj + 2], s2);
      s3 = fmaf(Qm[(size_t)(jj + 3) * NROWS + i], coef[jj + 3], s3);
    }
    for (; jj < k; ++jj) s0 = fmaf(Qm[(size_t)jj * NROWS + i], coef[jj], s0);
    float s = (s0 + s1) + (s2 + s3);
    tval = hc - s;
    Qm[(size_t)k * NROWS + i] = tval;
#pragma unroll
    for (int c = 0; c < 10; ++c) yv[c] = Y[(size_t)i * MOUT + c];
    if (k == 1) h0 = Hm[i];
  }

  int np = (k == 1) ? 23 : 11;
  float p[23];
  p[0] = tval * tval;
#pragma unroll
  for (int c = 0; c < 10; ++c) p[1 + c] = tval * yv[c];
  if (k == 1) {
    p[11] = hc * hc;
    p[12] = h0 * hc;
#pragma unroll
    for (int c = 0; c < 10; ++c) p[13 + c] = hc * yv[c];
  }
  int wid = tid >> 6, lane = tid & 63;
  for (int c = 0; c < np; ++c) {
    float v = p[c];
    v += __shfl_xor(v, 32); v += __shfl_xor(v, 16); v += __shfl_xor(v, 8);
    v += __shfl_xor(v, 4);  v += __shfl_xor(v, 2);  v += __shfl_xor(v, 1);
    if (lane == 0) wred[wid][c] = v;
  }
  __syncthreads();
  if (tid < np) part2[b * 23 + tid] = wred[0][tid] + wred[1][tid] + wred[2][tid] + wred[3][tid];

  // ---- last-done block: finalize ----
  __syncthreads();
  if (tid == 0) {
    __threadfence();
    unsigned d = __hip_atomic_fetch_add(counter, 1u, __ATOMIC_ACQ_REL, __HIP_MEMORY_SCOPE_AGENT);
    lastFlag = (d == NTB - 1) ? 1 : 0;
  }
  __syncthreads();
  if (!lastFlag) return;
  if (tid == 0) { __threadfence(); *counter = 0u; }

  __shared__ float vals[23];
  __shared__ float bsh[KMAX * 10];
  if (tid < np) {
    float s = 0.f;
    for (int b2 = 0; b2 < NTB; ++b2) s += part2[b2 * 23 + tid];
    vals[tid] = s;
  }
  __syncthreads();
  float r2 = sqrtf(vals[0]);
  if (tid < k) Rm[tid * KMAX + k] = r1s[tid];
  if (tid == 0) { Rm[k * KMAX + k] = r2; r2g[k] = r2; }
  if (tid < 10) QT[k * 10 + tid] = vals[1 + tid] / r2;
  if (k == 0 && tid < 11) scal[1 + tid] = vals[tid];
  __syncthreads();
  if (k == 0) {
    if (tid < 10) outBeta[tid] = (1.0f / vals[0]) * vals[1 + tid];
  } else if (k == 1) {
    if (tid < 10) {
      float g00 = scal[1], g0y = scal[2 + tid];
      float s11 = vals[11], s01 = vals[12], s1y = vals[13 + tid];
      float det = g00 * s11 - s01 * s01;
      float i00 = s11 / det, i01 = -s01 / det, i11 = g00 / det;
      outBeta[tid]      = i00 * g0y + i01 * s1y;
      outBeta[10 + tid] = i01 * g0y + i11 * s1y;
    }
  } else {
    if (tid < 10) {
      for (int row = k; row >= 0; --row) {
        float s = QT[row * 10 + tid];
        for (int jj = row + 1; jj <= k; ++jj) s = fmaf(-Rm[row * KMAX + jj], bsh[jj * 10 + tid], s);
        float bv = s / Rm[row * KMAX + row];
        bsh[row * 10 + tid] = bv;
        outBeta[row * 10 + tid] = bv;
      }
    }
  }
}

// ---------------- host ----------------
extern "C" void kernel_launch(void* const* d_in, const int* in_sizes, int n_in,
                              void* d_out, int out_size, void* d_ws, size_t ws_size,
                              hipStream_t stream) {
  const float* X = (const float*)d_in[0];
  const float* Y = (const float*)d_in[1];
  float* out = (float*)d_out;
  float* outW    = out;
  float* outb    = out + (size_t)DIM * KMAX;
  float* outBeta = outb + KMAX;

  float* ws = (float*)d_ws;
  size_t off = 0;
  float* h_col = ws + off; off += (size_t)NROWS * CAND;
  float* Wr    = ws + off; off += TOT_W;
  float* br    = ws + off; off += 256;
  float* Hm    = ws + off; off += (size_t)KMAX * NROWS;
  float* Qm    = ws + off; off += (size_t)KMAX * NROWS;
  float* Rm    = ws + off; off += (size_t)KMAX * KMAX;
  float* QT    = ws + off; off += (size_t)KMAX * MOUT;
  float* r2g   = ws + off; off += KMAX;
  float* r1g   = ws + off; off += KMAX;
  float* part1 = ws + off; off += (size_t)NBLK * P1STRIDE;
  float* part2 = ws + off; off += (size_t)NTB * 23;
  float* scal  = ws + off; off += 16;
  int*   ibest = (int*)(ws + off); off += 4;
  unsigned* counters = (unsigned*)(ws + off); off += 4;  // [0]=gemm, [1]=qr_tf

  // precompute key chain on host (bit-exact JAX split semantics)
  uint32_t kws0[KMAX], kws1[KMAX], kbs0[KMAX], kbs1[KMAX];
  uint32_t key0 = 0u, key1 = 42u;
  for (int k = 0; k < KMAX; ++k) {
    uint32_t o0[3], o1[3];
    for (int t = 0; t < 3; ++t)
      threefry2x32(key0, key1, 0u, (uint32_t)t, &o0[t], &o1[t]);
    kws0[k] = o0[1]; kws1[k] = o1[1]; kbs0[k] = o0[2]; kbs1[k] = o1[2];
    key0 = o0[0]; key1 = o1[0];
  }

  init_kern<<<1, 64, 0, stream>>>(counters);
  gen_rand_kern<<<(TOT_W + TOT_B + 255) / 256, 256, 0, stream>>>(Wr, br, kws0[0], kws1[0], kbs0[0], kbs1[0]);

  for (int k = 0; k < KMAX; ++k) {
    gemm_score_kern<<<NBLK, 512, 0, stream>>>(X, Y, Hm, outBeta, Wr, br,
                                              h_col, part1, outW, outb, ibest,
                                              &counters[0], k - 1, k);
    qr_r1_kern<<<k + 1, 256, 0, stream>>>(h_col, Hm, Qm, r2g, r1g, ibest, k);
    bool genNext = (k + 1 < KMAX);
    int nb = genNext ? (NTB + GENB) : NTB;
    int kn = genNext ? (k + 1) : 0;
    qr_tf_kern<<<nb, 256, 0, stream>>>(h_col, Y, Hm, Qm, r2g, r1g, Rm, QT, scal,
                                       outBeta, part2, ibest, &counters[1],
                                       Wr, br, kws0[kn], kws1[kn], kbs0[kn], kbs1[kn], k);
  }
}